// Round 13
// baseline (322.451 us; speedup 1.0000x reference)
//
#include <hip/hip_runtime.h>
#include <math.h>

#define BATCH 1024
#define SEQ   200
#define DIN   128
#define DOUT  128

// async global->LDS, 16B per lane; LDS dest = wave-uniform base (+lane*16 by HW)
__device__ __forceinline__ void async_copy16(const void* g, void* l) {
    __builtin_amdgcn_global_load_lds((const __attribute__((address_space(1))) void*)g,
                                     (__attribute__((address_space(3))) void*)l,
                                     16, 0, 0);
}

// ---- K0: transpose S (one-time) + zero the atomic accumulators ----
__global__ __launch_bounds__(256) void k_transpose(const float* __restrict__ S,
                                                   float* __restrict__ ST,
                                                   float* __restrict__ acc0,
                                                   float* __restrict__ acc1) {
    int idx = blockIdx.x * 256 + threadIdx.x;   // 0..16383
    int d = idx >> 7, e = idx & 127;
    ST[e * DIN + d] = S[d * DOUT + e];
    if (idx < 600) { acc0[idx] = 0.f; acc1[idx] = 0.f; }   // re-zero every replay
}

// ---- K_scan: softmax prefix tables (logits identical for all b; only mask
//      length n differs). Per k: prefix max M[n], inv-denom iE[n]. ----
__global__ __launch_bounds__(256) void k_scan(const float* __restrict__ Bm,
                                              const float* __restrict__ a0,
                                              const float* __restrict__ a1,
                                              float* __restrict__ v,
                                              float* __restrict__ Mn,
                                              float* __restrict__ iEn, int iter) {
    __shared__ float sv[SEQ];
    const int k = blockIdx.x, t = threadIdx.x;
    if (t < SEQ) {
        float x = Bm[k * SEQ + t];
        if (iter >= 1) x += a0[k * SEQ + t];
        if (iter >= 2) x += a1[k * SEQ + t];
        sv[t] = x;
        v[k * SEQ + t] = x;
    }
    __syncthreads();
    if (t < SEQ) {
        const int n = t + 1;
        float m = -INFINITY, s = 0.f;
        for (int l = 0; l < n; ++l) {
            float x = sv[l];
            float nm = fmaxf(m, x);
            s = s * expf(m - nm) + expf(x - nm);
            m = nm;
        }
        Mn[k * 201 + n] = m;
        iEn[k * 201 + n] = 1.f / s;
    }
}

// ---- K_fused: one routing iteration, one batch b per block.
//      Round-13: A_b (100 KB) staged into LDS via async global_load_lds
//      (100 x 1KB wave-insts, ZERO VGPR cost, whole tile in flight ->
//      per-CU read demand ~25 TB/s chip-wide, HBM becomes the binder;
//      r4-r12's ~1.3-2 TB/s was VGPR/occupancy-limited in-flight depth).
//      All A consumers read LDS:
//        WA: wave w rows 50w..50w+49, lane=dim-pair (row-uniform, no conflict)
//        PC: lane=row, per-lane ROTATED chunk order (j=(jj+t)&31) -> 8-way
//            bank conflict instead of 64-way; no shuffles.
//      119,424 B LDS -> 1 block/CU (4 sequential rounds; DMA hides latency,
//      not waves). (256,1): no occupancy chase, no spill. ----
__global__ __launch_bounds__(256, 1) void k_fused(
    const float* __restrict__ A,         // [B][200][128]
    const float* __restrict__ v,         // [3][200] logits
    const float* __restrict__ Mn,        // [3][201] prefix max
    const float* __restrict__ iEn,       // [3][201] prefix inv-denom
    const int* __restrict__ seq,         // [B]
    const float* __restrict__ S,         // [128][128]
    const float* __restrict__ ST,        // [128][128]
    float* __restrict__ accN,            // [600] atomic B_delta accumulator
    float* __restrict__ out, int iter) {
    __shared__ float  sA[SEQ * DIN];     // 102,400 B: A_b staged
    __shared__ float4 sW4[SEQ];          // 3,200 B: per-row weights
    __shared__ float  pB[4][3][DIN];     // 6,144 B: WA partials
    __shared__ float  sWA[3][DIN];       // 1,536 B
    __shared__ float  pb2[2][3][DIN];    // 3,072 B
    __shared__ float  sH[3][DIN];        // 1,536 B
    __shared__ float  sHS[3][DIN];       // 1,536 B   (total 119,424 B)

    const int t = threadIdx.x;
    const int lane = t & 63, w = t >> 6;
    const int b = blockIdx.x;
    const int n = seq[b];
    const float* Ab = A + (size_t)b * (SEQ * DIN);

    // (0a) async stage: 25 x 1KB per wave, linear LDS dest, no VGPR round-trip
    for (int i = 0; i < 25; ++i) {
        const int c = w * 25 + i;                 // chunk 0..99
        async_copy16(Ab + c * 256 + lane * 4, &sA[c * 256]);
    }

    // (0b) per-row weights from the prefix tables (overlaps the DMA)
    if (t < SEQ) {
        float w0 = 0.f, w1 = 0.f, w2 = 0.f;
        if (t < n) {
            w0 = expf(v[t]       - Mn[n])       * iEn[n];
            w1 = expf(v[200 + t] - Mn[201 + n]) * iEn[201 + n];
            w2 = expf(v[400 + t] - Mn[402 + n]) * iEn[402 + n];
        }
        sW4[t] = make_float4(w0, w1, w2, 0.f);
    }
    __syncthreads();   // drains DMA + weight stores

    // (1) WA from LDS: wave w rows 50w..50w+49; lane = dims 2lane,2lane+1
    {
        const float2* a2 = (const float2*)sA;     // row stride 64 float2
        float h00 = 0.f, h01 = 0.f, h10 = 0.f, h11 = 0.f, h20 = 0.f, h21 = 0.f;
        const int l0 = w * 50;
#pragma unroll 10
        for (int i = 0; i < 50; ++i) {
            const int l = l0 + i;
            float4 wv = sW4[l];
            float2 av = a2[l * 64 + lane];
            h00 = fmaf(wv.x, av.x, h00); h01 = fmaf(wv.x, av.y, h01);
            h10 = fmaf(wv.y, av.x, h10); h11 = fmaf(wv.y, av.y, h11);
            h20 = fmaf(wv.z, av.x, h20); h21 = fmaf(wv.z, av.y, h21);
        }
        pB[w][0][2 * lane] = h00; pB[w][0][2 * lane + 1] = h01;
        pB[w][1][2 * lane] = h10; pB[w][1][2 * lane + 1] = h11;
        pB[w][2][2 * lane] = h20; pB[w][2][2 * lane + 1] = h21;
    }
    __syncthreads();

    // (2) reduce WA across waves
    if (t < DIN) {
#pragma unroll
        for (int k = 0; k < 3; ++k)
            sWA[k][t] = pB[0][k][t] + pB[1][k][t] + pB[2][k][t] + pB[3][k][t];
    }
    __syncthreads();

    // (3) high_raw = WA @ S : e = t&127, hh = d-half; 8x8 named batches (L2)
    {
        const int e = t & 127, hh = t >> 7;
        const float* Scol = S + e;
        float g0 = 0.f, g1 = 0.f, g2 = 0.f;
        for (int g = 0; g < 8; ++g) {
            const int db = hh * 64 + g * 8;
            float s0 = Scol[(db + 0) * DOUT];
            float s1 = Scol[(db + 1) * DOUT];
            float s2 = Scol[(db + 2) * DOUT];
            float s3 = Scol[(db + 3) * DOUT];
            float s4 = Scol[(db + 4) * DOUT];
            float s5 = Scol[(db + 5) * DOUT];
            float s6 = Scol[(db + 6) * DOUT];
            float s7 = Scol[(db + 7) * DOUT];
#define HB_FMA(J, SV) \
            g0 = fmaf(sWA[0][db + J], SV, g0); \
            g1 = fmaf(sWA[1][db + J], SV, g1); \
            g2 = fmaf(sWA[2][db + J], SV, g2);
            HB_FMA(0, s0) HB_FMA(1, s1) HB_FMA(2, s2) HB_FMA(3, s3)
            HB_FMA(4, s4) HB_FMA(5, s5) HB_FMA(6, s6) HB_FMA(7, s7)
#undef HB_FMA
        }
        pb2[hh][0][e] = g0; pb2[hh][1][e] = g1; pb2[hh][2][e] = g2;
    }
    __syncthreads();

    // (3c) combine + squash; last iter writes out and exits (uniform)
    if (t < DIN) {
        float g0 = pb2[0][0][t] + pb2[1][0][t];
        float g1 = pb2[0][1][t] + pb2[1][1][t];
        float g2 = pb2[0][2][t] + pb2[1][2][t];
        float sq = g0 * g0 + g1 * g1 + g2 * g2;
        float scale = sq / (1.f + sq) / sqrtf(sq + 1e-9f);
        g0 *= scale; g1 *= scale; g2 *= scale;
        if (iter == 2) {
            size_t o = (size_t)b * 3 * DOUT + t;
            out[o] = g0; out[o + DOUT] = g1; out[o + 2 * DOUT] = g2;
        } else {
            sH[0][t] = g0; sH[1][t] = g1; sH[2][t] = g2;
        }
    }
    if (iter == 2) return;
    __syncthreads();

    // (4) hS = high @ S^T : d = t&127, hh = e-half; 8x8 named batches (L2)
    {
        const int d = t & 127, hh = t >> 7;
        const float* STcol = ST + d;
        float s0a = 0.f, s1a = 0.f, s2a = 0.f;
        for (int g = 0; g < 8; ++g) {
            const int eb = hh * 64 + g * 8;
            float s0 = STcol[(eb + 0) * DIN];
            float s1 = STcol[(eb + 1) * DIN];
            float s2 = STcol[(eb + 2) * DIN];
            float s3 = STcol[(eb + 3) * DIN];
            float s4 = STcol[(eb + 4) * DIN];
            float s5 = STcol[(eb + 5) * DIN];
            float s6 = STcol[(eb + 6) * DIN];
            float s7 = STcol[(eb + 7) * DIN];
#define HS_FMA(J, SV) \
            s0a = fmaf(sH[0][eb + J], SV, s0a); \
            s1a = fmaf(sH[1][eb + J], SV, s1a); \
            s2a = fmaf(sH[2][eb + J], SV, s2a);
            HS_FMA(0, s0) HS_FMA(1, s1) HS_FMA(2, s2) HS_FMA(3, s3)
            HS_FMA(4, s4) HS_FMA(5, s5) HS_FMA(6, s6) HS_FMA(7, s7)
#undef HS_FMA
        }
        pb2[hh][0][d] = s0a; pb2[hh][1][d] = s1a; pb2[hh][2][d] = s2a;
    }
    __syncthreads();
    if (t < DIN) {
        sHS[0][t] = pb2[0][0][t] + pb2[1][0][t];
        sHS[1][t] = pb2[0][1][t] + pb2[1][1][t];
        sHS[2][t] = pb2[0][2][t] + pb2[1][2][t];
    }
    __syncthreads();

    // (5) PC from LDS: thread = row t (<200); per-lane rotated chunk order
    //     j=(jj+t)&31 spreads the stride-512B row reads across 8 bank groups
    //     (8-way conflict vs 64-way linear). atomicAdd into accN (r11/r12).
    if (t < SEQ) {
        const float* row = &sA[t * DIN];
        float d0 = 0.f, d1 = 0.f, d2 = 0.f;
#pragma unroll 8
        for (int jj = 0; jj < 32; ++jj) {
            const int j = (jj + t) & 31;
            float4 u  = *(const float4*)(row + 4 * j);
            float4 x0 = *(const float4*)&sHS[0][4 * j];
            float4 x1 = *(const float4*)&sHS[1][4 * j];
            float4 x2 = *(const float4*)&sHS[2][4 * j];
            d0 += x0.x * u.x + x0.y * u.y + x0.z * u.z + x0.w * u.w;
            d1 += x1.x * u.x + x1.y * u.y + x1.z * u.z + x1.w * u.w;
            d2 += x2.x * u.x + x2.y * u.y + x2.z * u.z + x2.w * u.w;
        }
        atomicAdd(&accN[t],       d0);
        atomicAdd(&accN[200 + t], d1);
        atomicAdd(&accN[400 + t], d2);
    }
}

extern "C" void kernel_launch(void* const* d_in, const int* in_sizes, int n_in,
                              void* d_out, int out_size, void* d_ws, size_t ws_size,
                              hipStream_t stream) {
    const float* low_capsule = (const float*)d_in[0];   // [1024][200][128]
    const float* B_matrix    = (const float*)d_in[1];   // [1][3][200]
    const float* S_matrix    = (const float*)d_in[2];   // [128][128]
    const int*   seq_len     = (const int*)d_in[3];     // [1024]
    float* out = (float*)d_out;                         // [1024][3][128]

    float* ST   = (float*)d_ws;          // 16384
    float* vL   = ST + 16384;            // 600  (+pad)
    float* Mn   = vL + 640;              // 603  (+pad)
    float* iEn  = Mn + 640;              // 603  (+pad)
    float* acc0 = iEn + 640;             // 600  (+pad)
    float* acc1 = acc0 + 640;            // 600  (+pad)

    k_transpose<<<64, 256, 0, stream>>>(S_matrix, ST, acc0, acc1);

    // iter 0
    k_scan<<<3, 256, 0, stream>>>(B_matrix, acc0, acc1, vL, Mn, iEn, 0);
    k_fused<<<BATCH, 256, 0, stream>>>(low_capsule, vL, Mn, iEn, seq_len,
                                       S_matrix, ST, acc0, out, 0);
    // iter 1
    k_scan<<<3, 256, 0, stream>>>(B_matrix, acc0, acc1, vL, Mn, iEn, 1);
    k_fused<<<BATCH, 256, 0, stream>>>(low_capsule, vL, Mn, iEn, seq_len,
                                       S_matrix, ST, acc1, out, 1);
    // iter 2 (no PC / no accumulation)
    k_scan<<<3, 256, 0, stream>>>(B_matrix, acc0, acc1, vL, Mn, iEn, 2);
    k_fused<<<BATCH, 256, 0, stream>>>(low_capsule, vL, Mn, iEn, seq_len,
                                       S_matrix, ST, acc1, out, 2);
}